// Round 4
// baseline (149.510 us; speedup 1.0000x reference)
//
#include <hip/hip_runtime.h>
#include <hip/hip_bf16.h>
#include <stdint.h>

#define T_TOK 8192
#define D_IN  512
#define DINT  256
#define NE    8

typedef float f32x4 __attribute__((ext_vector_type(4)));
typedef short bf16x8 __attribute__((ext_vector_type(8)));
typedef unsigned short u16;
typedef unsigned short u16x4 __attribute__((ext_vector_type(4)));

// ws layout (bytes)
#define WS_CNT   0
#define WS_BTOK  1024                         // int [NE][T_TOK] slot ids (2t+rank)
#define WS_WP    (WS_BTOK + NE*T_TOK*4)       // f32 [T_TOK*2]
#define WS_F1B   (WS_WP + T_TOK*2*4)          // bf16 fc1
#define WS_F2B   (WS_F1B + NE*2*DINT*D_IN*2)  // bf16 fc2
#define WS_AA    (WS_F2B + NE*D_IN*DINT*2)    // bf16 act [16384][256]
#define WS_OP    (WS_AA + T_TOK*2*DINT*2)     // bf16 out_pairs [16384][512]
// end = WS_OP + 16,777,216 = 31,785,984 B

typedef const __attribute__((address_space(1))) void* gptr_t;
typedef __attribute__((address_space(3))) void* lptr_t;
#define GLL16(g, s) __builtin_amdgcn_global_load_lds((gptr_t)(g), (lptr_t)(s), 16, 0, 0)

static __device__ __forceinline__ u16 f32_bf16(float f) {
    union { float f; uint32_t u; } v; v.f = f;
    uint32_t u = v.u;
    uint32_t r = (u + 0x7FFFu + ((u >> 16) & 1u)) >> 16;   // RTNE
    return (u16)r;
}
static __device__ __forceinline__ float bf16_f32(u16 h) {
    union { uint32_t u; float f; } v; v.u = ((uint32_t)h) << 16; return v.f;
}

// ---------------- 1. f32 -> bf16 conversion of fc1, fc2 only ----------------
__global__ __launch_bounds__(256) void cvt_kernel(
    const float* __restrict__ fc1, const float* __restrict__ fc2,
    u16* __restrict__ f1b, u16* __restrict__ f2b)
{
    const int N1 = NE * 2 * DINT * D_IN / 4;   // 524,288 float4
    const int N2 = NE * D_IN * DINT / 4;       // 262,144
    const int total = N1 + N2;
    for (int i = blockIdx.x * 256 + threadIdx.x; i < total; i += gridDim.x * 256) {
        const float4* s; u16* d; int j;
        if (i < N1) { s = (const float4*)fc1; d = f1b; j = i; }
        else        { s = (const float4*)fc2; d = f2b; j = i - N1; }
        float4 v = s[j];
        u16x4 o;
        o.x = f32_bf16(v.x); o.y = f32_bf16(v.y);
        o.z = f32_bf16(v.z); o.w = f32_bf16(v.w);
        *(u16x4*)&d[(size_t)j * 4] = o;
    }
}

// ---------------- 2. gate: 64 tokens/block, 4-way k-split ----------------
__global__ __launch_bounds__(256) void gate_kernel(
    const float* __restrict__ x, const float* __restrict__ wg,
    int* __restrict__ cnt, int* __restrict__ btok, float* __restrict__ wpair)
{
    __shared__ float wgl[NE * D_IN];
    __shared__ float part[256 * 9];
    __shared__ int ecnt[NE];
    __shared__ int gbase[NE];

    const int tid = threadIdx.x;
    const int tl  = tid & 63;
    const int kq  = tid >> 6;
    const int t   = blockIdx.x * 64 + tl;

    for (int i = tid; i < NE * D_IN; i += 256) wgl[i] = wg[i];
    if (tid < NE) ecnt[tid] = 0;
    __syncthreads();

    float acc[NE];
#pragma unroll
    for (int e = 0; e < NE; e++) acc[e] = 0.f;
    const float* xr = x + (size_t)t * D_IN + kq * 128;
#pragma unroll
    for (int i = 0; i < 32; ++i) {
        float4 v = *(const float4*)&xr[i * 4];
#pragma unroll
        for (int e = 0; e < NE; e++) {
            float4 w = *(const float4*)&wgl[e * D_IN + kq * 128 + i * 4];
            acc[e] = fmaf(v.x, w.x, fmaf(v.y, w.y,
                     fmaf(v.z, w.z, fmaf(v.w, w.w, acc[e]))));
        }
    }
#pragma unroll
    for (int e = 0; e < NE; e++) part[tid * 9 + e] = acc[e];
    __syncthreads();

    int i1 = 0, i2 = -1, lp1 = 0, lp2 = 0;
    if (tid < 64) {
        float s8[NE];
#pragma unroll
        for (int e = 0; e < NE; e++)
            s8[e] = part[tid * 9 + e] + part[(64 + tid) * 9 + e]
                  + part[(128 + tid) * 9 + e] + part[(192 + tid) * 9 + e];
        float m = s8[0];
#pragma unroll
        for (int e = 1; e < NE; e++) m = fmaxf(m, s8[e]);
        float p[NE], s = 0.f;
#pragma unroll
        for (int e = 0; e < NE; e++) { p[e] = expf(s8[e] - m); s += p[e]; }
        float inv = 1.f / s;
        float v1 = p[0];
#pragma unroll
        for (int e = 1; e < NE; e++) if (p[e] > v1) { v1 = p[e]; i1 = e; }
        float v2 = -1.f;
#pragma unroll
        for (int e = 0; e < NE; e++) if (e != i1 && p[e] > v2) { v2 = p[e]; i2 = e; }
        wpair[2 * t]     = v1 * inv;
        wpair[2 * t + 1] = v2 * inv;
        lp1 = atomicAdd(&ecnt[i1], 1);
        lp2 = atomicAdd(&ecnt[i2], 1);
    }
    __syncthreads();
    if (tid < NE) gbase[tid] = atomicAdd(&cnt[tid], ecnt[tid]);
    __syncthreads();
    if (tid < 64) {
        btok[i1 * T_TOK + gbase[i1] + lp1] = 2 * t;
        btok[i2 * T_TOK + gbase[i2] + lp2] = 2 * t + 1;
    }
}

// ---------------- 3. fc1 + GLU: aact[slot][256] ----------------
// grid 512 = 8 experts x {ns(2) x mt0(16)}; block 256 thr (4 waves).
// Wave owns 16-row M-strip; A gathered from x (f32->bf16 in-reg);
// B (fc1 N-slice 256 rows) staged 16KB/step, dbuf. LDS 33KB -> 4 blocks/CU.
__global__ __launch_bounds__(256, 4) void fc1_kernel(
    const float* __restrict__ x, const u16* __restrict__ f1b,
    const int* __restrict__ cnt, const int* __restrict__ btok,
    u16* __restrict__ aact)
{
    __shared__ __align__(16) u16 bbuf[2][8192];   // 2 x 16KB
    __shared__ int slot_l[64];

    const int bid = blockIdx.x;
    const int e   = bid & 7;                      // XCD pinning
    const int sub = bid >> 3;                     // 0..63
    const int ns  = sub & 1;
    const int mt0 = sub >> 1;                     // 0..31
    const int n   = cnt[e];

    const int tid = threadIdx.x;
    const int wv  = tid >> 6, lane = tid & 63;
    const int l15 = lane & 15, lhi = lane >> 4;

    const u16* w1 = f1b + (size_t)e * (2 * DINT) * D_IN;
    const u16* bsrc0, * bsrc1, * bsrc2, * bsrc3;
    {
        int f0 = wv * 4;
        int r0 = (f0 < 8) ? (ns * 128 + f0 * 16) : (256 + ns * 128 + (f0 - 8) * 16);
        bsrc0 = w1 + (size_t)(r0 + l15) * D_IN + lhi * 8;
        bsrc1 = bsrc0 + (size_t)16 * D_IN;
        bsrc2 = bsrc0 + (size_t)32 * D_IN;
        bsrc3 = bsrc0 + (size_t)48 * D_IN;
    }
#define STAGE1(BUF, K0) {                                           \
    GLL16(bsrc0 + (K0), &bbuf[BUF][(wv * 4 + 0) * 512]);            \
    GLL16(bsrc1 + (K0), &bbuf[BUF][(wv * 4 + 1) * 512]);            \
    GLL16(bsrc2 + (K0), &bbuf[BUF][(wv * 4 + 2) * 512]);            \
    GLL16(bsrc3 + (K0), &bbuf[BUF][(wv * 4 + 3) * 512]); }

    for (int mt = mt0; mt * 64 < n; mt += 32) {
        const int row0  = mt * 64;
        const int nrows = (n - row0 < 64) ? (n - row0) : 64;
        __syncthreads();
        if (tid < 64) slot_l[tid] = btok[e * T_TOK + row0 + ((tid < nrows) ? tid : 0)];
        __syncthreads();

        const int myslot = slot_l[wv * 16 + l15];
        const float* xrow = x + (size_t)(myslot >> 1) * D_IN + lhi * 8;

        STAGE1(0, 0);
        f32x4 acc[16];
#pragma unroll
        for (int f = 0; f < 16; f++) acc[f] = (f32x4)0.f;

#pragma unroll
        for (int ks = 0; ks < 16; ks++) {
            const int k0 = ks * 32;
            __syncthreads();
            if (ks < 15) STAGE1((ks & 1) ^ 1, k0 + 32);
            float4 xa = *(const float4*)&xrow[k0];
            float4 xc = *(const float4*)&xrow[k0 + 4];
            bf16x8 a;
            a[0] = (short)f32_bf16(xa.x); a[1] = (short)f32_bf16(xa.y);
            a[2] = (short)f32_bf16(xa.z); a[3] = (short)f32_bf16(xa.w);
            a[4] = (short)f32_bf16(xc.x); a[5] = (short)f32_bf16(xc.y);
            a[6] = (short)f32_bf16(xc.z); a[7] = (short)f32_bf16(xc.w);
#pragma unroll
            for (int f = 0; f < 16; f++) {
                bf16x8 b = *(const bf16x8*)&bbuf[ks & 1][f * 512 + lane * 8];
                acc[f] = __builtin_amdgcn_mfma_f32_16x16x32_bf16(a, b, acc[f], 0, 0, 0);
            }
        }

        // GLU epilogue: C layout row=lhi*4+r (token), col=l15 (fc1-row)
        const int rbase = wv * 16 + lhi * 4;
#pragma unroll
        for (int r = 0; r < 4; r++) {
            int row = rbase + r;
            if (row < nrows) {
                int slot = slot_l[row];
                u16* ao = aact + (size_t)slot * DINT + ns * 128 + l15;
#pragma unroll
                for (int f = 0; f < 8; f++) {
                    float y = acc[f][r], g = acc[f + 8][r];
                    float v = y * g / (1.f + __expf(-g));
                    ao[f * 16] = f32_bf16(v);
                }
            }
        }
    }
#undef STAGE1
}

// ---------------- 4. fc2: opair[slot][512] ----------------
__global__ __launch_bounds__(256, 4) void fc2_kernel(
    const u16* __restrict__ aact, const u16* __restrict__ f2b,
    const int* __restrict__ cnt, const int* __restrict__ btok,
    u16* __restrict__ opair)
{
    __shared__ __align__(16) u16 bbuf[2][8192];
    __shared__ int slot_l[64];

    const int bid = blockIdx.x;
    const int e   = bid & 7;
    const int sub = bid >> 3;
    const int ns  = sub & 1;
    const int mt0 = sub >> 1;
    const int n   = cnt[e];

    const int tid = threadIdx.x;
    const int wv  = tid >> 6, lane = tid & 63;
    const int l15 = lane & 15, lhi = lane >> 4;

    const u16* w2 = f2b + (size_t)e * D_IN * DINT;
    const u16* bsrc0 = w2 + (size_t)(ns * 256 + wv * 64 + l15) * DINT + lhi * 8;
    const u16* bsrc1 = bsrc0 + (size_t)16 * DINT;
    const u16* bsrc2 = bsrc0 + (size_t)32 * DINT;
    const u16* bsrc3 = bsrc0 + (size_t)48 * DINT;
#define STAGE2(BUF, K0) {                                           \
    GLL16(bsrc0 + (K0), &bbuf[BUF][(wv * 4 + 0) * 512]);            \
    GLL16(bsrc1 + (K0), &bbuf[BUF][(wv * 4 + 1) * 512]);            \
    GLL16(bsrc2 + (K0), &bbuf[BUF][(wv * 4 + 2) * 512]);            \
    GLL16(bsrc3 + (K0), &bbuf[BUF][(wv * 4 + 3) * 512]); }

    for (int mt = mt0; mt * 64 < n; mt += 32) {
        const int row0  = mt * 64;
        const int nrows = (n - row0 < 64) ? (n - row0) : 64;
        __syncthreads();
        if (tid < 64) slot_l[tid] = btok[e * T_TOK + row0 + ((tid < nrows) ? tid : 0)];
        __syncthreads();

        const int myslot = slot_l[wv * 16 + l15];
        const u16* arow = aact + (size_t)myslot * DINT + lhi * 8;

        STAGE2(0, 0);
        f32x4 acc[16];
#pragma unroll
        for (int f = 0; f < 16; f++) acc[f] = (f32x4)0.f;

#pragma unroll
        for (int ks = 0; ks < 8; ks++) {
            const int k0 = ks * 32;
            __syncthreads();
            if (ks < 7) STAGE2((ks & 1) ^ 1, k0 + 32);
            bf16x8 a = *(const bf16x8*)&arow[k0];
#pragma unroll
            for (int f = 0; f < 16; f++) {
                bf16x8 b = *(const bf16x8*)&bbuf[ks & 1][f * 512 + lane * 8];
                acc[f] = __builtin_amdgcn_mfma_f32_16x16x32_bf16(a, b, acc[f], 0, 0, 0);
            }
        }

        const int rbase = wv * 16 + lhi * 4;
#pragma unroll
        for (int r = 0; r < 4; r++) {
            int row = rbase + r;
            if (row < nrows) {
                int slot = slot_l[row];
                u16* oo = opair + (size_t)slot * D_IN + ns * 256 + l15;
#pragma unroll
                for (int f = 0; f < 16; f++)
                    oo[f * 16] = f32_bf16(acc[f][r]);
            }
        }
    }
#undef STAGE2
}

// ---------------- 5. combine ----------------
__global__ __launch_bounds__(256) void combine_kernel(
    const u16* __restrict__ opair, const float* __restrict__ wpair,
    float* __restrict__ out)
{
    int idx = blockIdx.x * 256 + threadIdx.x;
    int t  = idx >> 6;
    int c8 = (idx & 63) * 8;
    float w0 = wpair[2 * t], w1 = wpair[2 * t + 1];
    bf16x8 a = *(const bf16x8*)&opair[(size_t)(2 * t) * D_IN + c8];
    bf16x8 b = *(const bf16x8*)&opair[(size_t)(2 * t + 1) * D_IN + c8];
    float4 o0, o1;
#pragma unroll
    for (int j = 0; j < 4; j++) {
        o0[j] = w0 * bf16_f32((u16)a[j])     + w1 * bf16_f32((u16)b[j]);
        o1[j] = w0 * bf16_f32((u16)a[j + 4]) + w1 * bf16_f32((u16)b[j + 4]);
    }
    float* orow = out + (size_t)t * D_IN + c8;
    *(float4*)orow = o0;
    *(float4*)(orow + 4) = o1;
}

// ---------------- launch ----------------
extern "C" void kernel_launch(void* const* d_in, const int* in_sizes, int n_in,
                              void* d_out, int out_size, void* d_ws, size_t ws_size,
                              hipStream_t stream) {
    const float* x   = (const float*)d_in[0];
    const float* wg  = (const float*)d_in[1];
    const float* fc1 = (const float*)d_in[2];
    const float* fc2 = (const float*)d_in[3];
    float* out = (float*)d_out;
    char* ws = (char*)d_ws;

    int*   cnt   = (int*)(ws + WS_CNT);
    int*   btok  = (int*)(ws + WS_BTOK);
    float* wpair = (float*)(ws + WS_WP);
    u16*   f1b   = (u16*)(ws + WS_F1B);
    u16*   f2b   = (u16*)(ws + WS_F2B);
    u16*   aact  = (u16*)(ws + WS_AA);
    u16*   opair = (u16*)(ws + WS_OP);

    hipMemsetAsync(cnt, 0, 1024, stream);

    cvt_kernel<<<1024, 256, 0, stream>>>(fc1, fc2, f1b, f2b);
    gate_kernel<<<T_TOK / 64, 256, 0, stream>>>(x, wg, cnt, btok, wpair);
    fc1_kernel<<<512, 256, 0, stream>>>(x, f1b, cnt, btok, aact);
    fc2_kernel<<<512, 256, 0, stream>>>(aact, f2b, cnt, btok, opair);
    combine_kernel<<<T_TOK * (D_IN / 8) / 256, 256, 0, stream>>>(opair, wpair, out);
}